// Round 2
// baseline (256.634 us; speedup 1.0000x reference)
//
#include <hip/hip_runtime.h>

#define HH 128
#define WW 128
#define CC 64
#define OO 64
#define HWSZ (HH*WW)

// ---------------------------------------------------------------------------
// Kernel 0: transpose w_dcn[o][c][k] -> wt[k][c][o]  (per-k slice contiguous,
// coalesced LDS staging in the deform kernel)
// ---------------------------------------------------------------------------
__global__ __launch_bounds__(256) void transpose_wdcn(const float* __restrict__ wd,
                                                      float* __restrict__ wt) {
    int i = blockIdx.x * 256 + threadIdx.x;
    if (i < OO * CC * 9) {
        int o = i / 576;
        int r = i - o * 576;
        int c = r / 9;
        int k = r - c * 9;
        wt[k * (CC * OO) + c * OO + o] = wd[i];
    }
}

// ---------------------------------------------------------------------------
// Kernel 1: offset conv — 3x3, pad 1. Thread = one (b,h,w) pixel, one group
// of 9 output channels (grid.y selects group). Weight indices are
// wave-uniform -> scalar loads; VALU does only the FMAs.
// ---------------------------------------------------------------------------
__global__ __launch_bounds__(256) void offset_conv(const float* __restrict__ x,
                                                   const float* __restrict__ w_off,
                                                   const float* __restrict__ b_off,
                                                   float* __restrict__ off) {
    int t = blockIdx.x * 256 + threadIdx.x;       // pixel id over B*H*W
    int g = blockIdx.y;                            // oc group: oc = g*9 .. g*9+8
    int w = t & (WW - 1);
    int h = (t >> 7) & (HH - 1);
    int b = t >> 14;

    const float* xb = x + b * (CC * HWSZ);
    float acc[9];
#pragma unroll
    for (int j = 0; j < 9; ++j) acc[j] = b_off[g * 9 + j];

    const float* wbase = w_off + g * 9 * 576;
    for (int c = 0; c < CC; ++c) {
        float tap[9];
        const float* xc = xb + c * HWSZ;
#pragma unroll
        for (int ky = 0; ky < 3; ++ky) {
            int yy = h + ky - 1;
            bool yok = (unsigned)yy < (unsigned)HH;
#pragma unroll
            for (int kx = 0; kx < 3; ++kx) {
                int xx = w + kx - 1;
                bool ok = yok && ((unsigned)xx < (unsigned)WW);
                tap[ky * 3 + kx] = ok ? xc[yy * WW + xx] : 0.0f;
            }
        }
        const float* wp = wbase + c * 9;   // uniform -> scalar loads
#pragma unroll
        for (int oc = 0; oc < 9; ++oc) {
#pragma unroll
            for (int j = 0; j < 9; ++j)
                acc[oc] = fmaf(tap[j], wp[oc * 576 + j], acc[oc]);
        }
    }
    float* op = off + ((b * 18 + g * 9) * HWSZ) + (h * WW) + w;
#pragma unroll
    for (int oc = 0; oc < 9; ++oc) op[oc * HWSZ] = acc[oc];
}

// ---------------------------------------------------------------------------
// Kernel 2: deformable conv. Block = one b, one row h, 64 consecutive pixels,
// all 64 output channels. Per kernel-position k: corner precompute (64 lanes)
// -> bilinear sample val_s[c][pix] (coalesced-ish gathers) -> 64x64x64
// register-blocked FMA (4o x 4pix per thread, float4 LDS reads).
// ---------------------------------------------------------------------------
__global__ __launch_bounds__(256) void deform_conv(const float* __restrict__ x,
                                                   const float* __restrict__ off,
                                                   const float* __restrict__ wt,
                                                   const float* __restrict__ b_dcn,
                                                   float* __restrict__ out) {
    int b  = blockIdx.z;
    int h  = blockIdx.y;
    int w0 = blockIdx.x * 64;
    int t  = threadIdx.x;

    __shared__ float off_s[18 * 64];
    __shared__ __attribute__((aligned(16))) float wk_s[CC * OO];
    __shared__ __attribute__((aligned(16))) float val_s[CC * 64];
    __shared__ float cw_s[4][64];
    __shared__ int   ci_s[4][64];

    const float* offb = off + b * (18 * HWSZ) + h * WW + w0;
    for (int i = t; i < 18 * 64; i += 256)
        off_s[i] = offb[(i >> 6) * HWSZ + (i & 63)];

    int og = t >> 4;   // o = og*4 + j
    int pg = t & 15;   // pix = pg*4 + i
    float acc[16];
#pragma unroll
    for (int j = 0; j < 4; ++j) {
        float bb = b_dcn[og * 4 + j];
        acc[j * 4 + 0] = bb; acc[j * 4 + 1] = bb;
        acc[j * 4 + 2] = bb; acc[j * 4 + 3] = bb;
    }

    const float* xb = x + b * (CC * HWSZ);
    __syncthreads();

    for (int k = 0; k < 9; ++k) {
        // ---- corner precompute: lane t<64 handles pixel (h, w0+t) ----
        if (t < 64) {
            int ky = k / 3, kx = k - ky * 3;
            float dy = off_s[(2 * k) * 64 + t];
            float dx = off_s[(2 * k + 1) * 64 + t];
            float py = (float)(h + ky - 1) + dy;
            float px = (float)(w0 + t + kx - 1) + dx;
            float y0f = floorf(py), x0f = floorf(px);
            float wy = py - y0f, wx = px - x0f;
            int y0 = (int)y0f, x0 = (int)x0f;
            int y1 = y0 + 1, x1 = x0 + 1;
            float wy0 = 1.0f - wy, wx0 = 1.0f - wx;
            bool vy0 = (unsigned)y0 < (unsigned)HH, vy1 = (unsigned)y1 < (unsigned)HH;
            bool vx0 = (unsigned)x0 < (unsigned)WW, vx1 = (unsigned)x1 < (unsigned)WW;
            int y0c = min(max(y0, 0), HH - 1), y1c = min(max(y1, 0), HH - 1);
            int x0c = min(max(x0, 0), WW - 1), x1c = min(max(x1, 0), WW - 1);
            cw_s[0][t] = (vy0 && vx0) ? wy0 * wx0 : 0.0f;  ci_s[0][t] = y0c * WW + x0c;
            cw_s[1][t] = (vy0 && vx1) ? wy0 * wx  : 0.0f;  ci_s[1][t] = y0c * WW + x1c;
            cw_s[2][t] = (vy1 && vx0) ? wy  * wx0 : 0.0f;  ci_s[2][t] = y1c * WW + x0c;
            cw_s[3][t] = (vy1 && vx1) ? wy  * wx  : 0.0f;  ci_s[3][t] = y1c * WW + x1c;
        }
        // ---- stage this k's weight slice wt[k][c][o] (coalesced) ----
        const float* wkp = wt + k * (CC * OO);
#pragma unroll
        for (int i = 0; i < 16; ++i) wk_s[i * 256 + t] = wkp[i * 256 + t];
        __syncthreads();

        // ---- bilinear sampling: val_s[c*64+pix], lanes sweep pix ----
#pragma unroll 4
        for (int i = 0; i < 16; ++i) {
            int idx = i * 256 + t;
            int pix = idx & 63;
            int c   = idx >> 6;
            const float* xc = xb + c * HWSZ;
            float v = cw_s[0][pix] * xc[ci_s[0][pix]]
                    + cw_s[1][pix] * xc[ci_s[1][pix]]
                    + cw_s[2][pix] * xc[ci_s[2][pix]]
                    + cw_s[3][pix] * xc[ci_s[3][pix]];
            val_s[idx] = v;
        }
        __syncthreads();

        // ---- 64x64 x 64x64 accumulate: 4o x 4pix per thread ----
#pragma unroll 8
        for (int c = 0; c < CC; ++c) {
            const float4 wv = *(const float4*)&wk_s[(c << 6) + (og << 2)];
            const float4 vv = *(const float4*)&val_s[(c << 6) + (pg << 2)];
            acc[0]  = fmaf(wv.x, vv.x, acc[0]);
            acc[1]  = fmaf(wv.x, vv.y, acc[1]);
            acc[2]  = fmaf(wv.x, vv.z, acc[2]);
            acc[3]  = fmaf(wv.x, vv.w, acc[3]);
            acc[4]  = fmaf(wv.y, vv.x, acc[4]);
            acc[5]  = fmaf(wv.y, vv.y, acc[5]);
            acc[6]  = fmaf(wv.y, vv.z, acc[6]);
            acc[7]  = fmaf(wv.y, vv.w, acc[7]);
            acc[8]  = fmaf(wv.z, vv.x, acc[8]);
            acc[9]  = fmaf(wv.z, vv.y, acc[9]);
            acc[10] = fmaf(wv.z, vv.z, acc[10]);
            acc[11] = fmaf(wv.z, vv.w, acc[11]);
            acc[12] = fmaf(wv.w, vv.x, acc[12]);
            acc[13] = fmaf(wv.w, vv.y, acc[13]);
            acc[14] = fmaf(wv.w, vv.z, acc[14]);
            acc[15] = fmaf(wv.w, vv.w, acc[15]);
        }
        __syncthreads();
    }

    // ---- write out[b][o][h][w0 + pg*4 + i] ----
    float* ob = out + (b * OO + og * 4) * HWSZ + h * WW + w0 + (pg << 2);
#pragma unroll
    for (int j = 0; j < 4; ++j) {
        float4 r = make_float4(acc[j * 4 + 0], acc[j * 4 + 1],
                               acc[j * 4 + 2], acc[j * 4 + 3]);
        *(float4*)(ob + j * HWSZ) = r;
    }
}

// ---------------------------------------------------------------------------
extern "C" void kernel_launch(void* const* d_in, const int* in_sizes, int n_in,
                              void* d_out, int out_size, void* d_ws, size_t ws_size,
                              hipStream_t stream) {
    const float* x     = (const float*)d_in[0];
    const float* w_off = (const float*)d_in[1];
    const float* b_off = (const float*)d_in[2];
    const float* w_dcn = (const float*)d_in[3];
    const float* b_dcn = (const float*)d_in[4];
    float* out = (float*)d_out;

    float* wt     = (float*)d_ws;                           // 36864 floats = 147456 B
    float* offbuf = (float*)((char*)d_ws + 147456);         // 4*18*128*128 floats

    hipLaunchKernelGGL(transpose_wdcn, dim3(144), dim3(256), 0, stream, w_dcn, wt);
    hipLaunchKernelGGL(offset_conv, dim3(256, 2), dim3(256), 0, stream,
                       x, w_off, b_off, offbuf);
    hipLaunchKernelGGL(deform_conv, dim3(2, 128, 4), dim3(256), 0, stream,
                       x, offbuf, wt, b_dcn, out);
}

// Round 3
// 176.643 us; speedup vs baseline: 1.4528x; 1.4528x over previous
//
#include <hip/hip_runtime.h>

#define BB 4
#define HH 128
#define WW 128
#define CC 64
#define OO 64
#define HWSZ (HH*WW)

typedef short bf16x8 __attribute__((ext_vector_type(8)));
typedef float f32x4  __attribute__((ext_vector_type(4)));

__device__ __forceinline__ unsigned short f2bf(float f) {
    unsigned u = __float_as_uint(f);
    u = (u + 0x7FFFu + ((u >> 16) & 1u)) >> 16;
    return (unsigned short)u;
}

// ---------------------------------------------------------------------------
// K0: x NCHW fp32 -> NHWC fp32 (LDS tile, +1 pad: conflict-free both phases)
// ---------------------------------------------------------------------------
__global__ __launch_bounds__(256) void transpose_x(const float* __restrict__ x,
                                                   float* __restrict__ xh) {
    __shared__ float tile[64 * 65];
    int w0 = blockIdx.x * 64, h = blockIdx.y, b = blockIdx.z;
    int t = threadIdx.x;
    const float* xb = x + ((long)b * CC * HWSZ) + h * WW + w0;
#pragma unroll
    for (int i = 0; i < 16; ++i) {
        int idx = i * 256 + t; int c = idx >> 6, w = idx & 63;
        tile[c * 65 + w] = xb[c * HWSZ + w];
    }
    __syncthreads();
    float* xo = xh + ((long)(b * HH + h) * WW + w0) * CC;
#pragma unroll
    for (int i = 0; i < 16; ++i) {
        int idx = i * 256 + t; int w = idx >> 6, c = idx & 63;
        xo[w * CC + c] = tile[c * 65 + w];
    }
}

// ---------------------------------------------------------------------------
// K1: weight repack -> bf16.  wdt[k][o][c] (64x64/k), wot[k][oc(32,pad)][c]
// ---------------------------------------------------------------------------
__global__ __launch_bounds__(256) void prep_w(const float* __restrict__ wd,
                                              const float* __restrict__ wo,
                                              unsigned short* __restrict__ wdt,
                                              unsigned short* __restrict__ wot) {
    int i = blockIdx.x * 256 + threadIdx.x;
    if (i < 9 * 64 * 64) {
        int k = i >> 12, r = i & 4095, o = r >> 6, c = r & 63;
        wdt[i] = f2bf(wd[(o * 64 + c) * 9 + k]);
    }
    int j = i - 9 * 64 * 64;
    if (j >= 0 && j < 9 * 32 * 64) {
        int k = j >> 11, r = j & 2047, oc = r >> 6, c = r & 63;
        wot[j] = f2bf(oc < 18 ? wo[(oc * 64 + c) * 9 + k] : 0.0f);
    }
}

// ---------------------------------------------------------------------------
// K2: offset conv as implicit-GEMM MFMA. Block = (b,h,64px). Out: px x 18oc
// (N padded to 32). Per k: stage shifted x row (bf16) + W slice, 2 chunks.
// offb layout NHWC: [b][h][w][18] fp32.
// ---------------------------------------------------------------------------
__global__ __launch_bounds__(256) void offset_mfma(const float* __restrict__ xh,
                                                   const unsigned short* __restrict__ wot,
                                                   const float* __restrict__ b_off,
                                                   float* __restrict__ offb) {
    __shared__ unsigned short vs[64 * 72];   // A: val[px][c] bf16, row pad 72
    __shared__ unsigned short ws[32 * 72];   // B: w_off slice [oc][c]
    int w0 = blockIdx.x * 64, h = blockIdx.y, b = blockIdx.z;
    int t = threadIdx.x;
    int l = t & 63, wv = t >> 6;
    int otile = wv & 1;
    int pt0 = (wv >> 1) * 2;
    int px = t & 63, ch = (t >> 6) * 16;

    f32x4 acc0 = {0.f, 0.f, 0.f, 0.f}, acc1 = {0.f, 0.f, 0.f, 0.f};

    for (int k = 0; k < 9; ++k) {
        int ky = k / 3, kx = k - ky * 3;
        // stage B slice: 2048 bf16 = 256 uint4, one per thread
        {
            uint4 v = ((const uint4*)(wot + k * 2048))[t];
            int o = t >> 3, cb = (t & 7) * 8;
            *(uint4*)&ws[o * 72 + cb] = v;
        }
        // stage A: shifted x row, fp32 -> bf16, zero at image border
        {
            int y = h + ky - 1, xc = w0 + px + kx - 1;
            bool ok = ((unsigned)y < HH) && ((unsigned)xc < WW);
            const f32x4* p = (const f32x4*)(xh + ((long)(b * HH + y) * WW + xc) * CC + ch);
#pragma unroll
            for (int jj = 0; jj < 4; ++jj) {
                f32x4 v = ok ? p[jj] : f32x4{0.f, 0.f, 0.f, 0.f};
                ushort4 u; u.x = f2bf(v.x); u.y = f2bf(v.y); u.z = f2bf(v.z); u.w = f2bf(v.w);
                *(ushort4*)&vs[px * 72 + ch + jj * 4] = u;
            }
        }
        __syncthreads();
#pragma unroll
        for (int c0 = 0; c0 < 64; c0 += 32) {
            int fo = c0 + (l >> 4) * 8;
            bf16x8 bf = *(const bf16x8*)&ws[(otile * 16 + (l & 15)) * 72 + fo];
            bf16x8 a0 = *(const bf16x8*)&vs[((pt0    ) * 16 + (l & 15)) * 72 + fo];
            bf16x8 a1 = *(const bf16x8*)&vs[((pt0 + 1) * 16 + (l & 15)) * 72 + fo];
            acc0 = __builtin_amdgcn_mfma_f32_16x16x32_bf16(a0, bf, acc0, 0, 0, 0);
            acc1 = __builtin_amdgcn_mfma_f32_16x16x32_bf16(a1, bf, acc1, 0, 0, 0);
        }
        __syncthreads();
    }
    int oc = otile * 16 + (l & 15);
    if (oc < 18) {
        float bo = b_off[oc];
        int q = l >> 4;
        float* dst = offb + ((long)(b * HH + h) * WW + w0) * 18 + oc;
#pragma unroll
        for (int r = 0; r < 4; ++r) {
            dst[((pt0    ) * 16 + q * 4 + r) * 18] = acc0[r] + bo;
            dst[((pt0 + 1) * 16 + q * 4 + r) * 18] = acc1[r] + bo;
        }
    }
}

// ---------------------------------------------------------------------------
// K3: deform conv. Block = (b,h,64px) -> out 64px x 64o. Per k: bilinear
// sample from NHWC x (channel-contiguous dwordx4 corners) -> bf16 LDS in
// MFMA-A layout; W slice -> LDS; 8 MFMA/wave (4 px-tiles x 2 K-chunks).
// ---------------------------------------------------------------------------
__global__ __launch_bounds__(256) void deform_mfma(const float* __restrict__ xh,
                                                   const float* __restrict__ offb,
                                                   const unsigned short* __restrict__ wdt,
                                                   const float* __restrict__ b_dcn,
                                                   float* __restrict__ out) {
    __shared__ float offs[64 * 18];          // per-px offsets, flat copy
    __shared__ unsigned short vs[64 * 72];   // A: val[px][c] bf16
    __shared__ unsigned short wds[64 * 72];  // B: w[o][c] bf16 (this k)
    int w0 = blockIdx.x * 64, h = blockIdx.y, b = blockIdx.z;
    int t = threadIdx.x;
    int l = t & 63, wv = t >> 6;
    int px = t & 63, ch = (t >> 6) * 16;

    const float* osrc = offb + ((long)(b * HH + h) * WW + w0) * 18;
    for (int i = t; i < 64 * 18; i += 256) offs[i] = osrc[i];

    f32x4 acc[4];
#pragma unroll
    for (int i = 0; i < 4; ++i) acc[i] = f32x4{0.f, 0.f, 0.f, 0.f};

    const float* xb = xh + (long)b * HWSZ * CC;
    __syncthreads();

    for (int k = 0; k < 9; ++k) {
        int ky = k / 3, kx = k - ky * 3;
        // stage W slice: 4096 bf16 = 512 uint4, 2 per thread
        {
            const uint4* src = (const uint4*)(wdt + k * 4096);
            uint4 v0 = src[t * 2], v1 = src[t * 2 + 1];
            int o = t >> 2, cb = (t & 3) * 16;
            *(uint4*)&wds[o * 72 + cb] = v0;
            *(uint4*)&wds[o * 72 + cb + 8] = v1;
        }
        // bilinear sample 16 channels for this thread's pixel
        {
            float dy = offs[px * 18 + 2 * k], dx = offs[px * 18 + 2 * k + 1];
            float py  = (float)(h + ky - 1) + dy;
            float pxf = (float)(w0 + px + kx - 1) + dx;
            float y0f = floorf(py), x0f = floorf(pxf);
            float wy = py - y0f, wx = pxf - x0f;
            int y0 = (int)y0f, x0 = (int)x0f, y1 = y0 + 1, x1 = x0 + 1;
            float wy0 = 1.f - wy, wx0 = 1.f - wx;
            bool vy0 = (unsigned)y0 < HH, vy1 = (unsigned)y1 < HH;
            bool vx0 = (unsigned)x0 < WW, vx1 = (unsigned)x1 < WW;
            int y0c = min(max(y0, 0), HH - 1), y1c = min(max(y1, 0), HH - 1);
            int x0c = min(max(x0, 0), WW - 1), x1c = min(max(x1, 0), WW - 1);
            float cw0 = (vy0 && vx0) ? wy0 * wx0 : 0.f;
            float cw1 = (vy0 && vx1) ? wy0 * wx  : 0.f;
            float cw2 = (vy1 && vx0) ? wy  * wx0 : 0.f;
            float cw3 = (vy1 && vx1) ? wy  * wx  : 0.f;
            const f32x4* p00 = (const f32x4*)(xb + (y0c * WW + x0c) * CC + ch);
            const f32x4* p01 = (const f32x4*)(xb + (y0c * WW + x1c) * CC + ch);
            const f32x4* p10 = (const f32x4*)(xb + (y1c * WW + x0c) * CC + ch);
            const f32x4* p11 = (const f32x4*)(xb + (y1c * WW + x1c) * CC + ch);
#pragma unroll
            for (int jj = 0; jj < 4; ++jj) {
                f32x4 v = cw0 * p00[jj] + cw1 * p01[jj] + cw2 * p10[jj] + cw3 * p11[jj];
                ushort4 u; u.x = f2bf(v.x); u.y = f2bf(v.y); u.z = f2bf(v.z); u.w = f2bf(v.w);
                *(ushort4*)&vs[px * 72 + ch + jj * 4] = u;
            }
        }
        __syncthreads();
#pragma unroll
        for (int c0 = 0; c0 < 64; c0 += 32) {
            int fo = c0 + (l >> 4) * 8;
            bf16x8 bfr = *(const bf16x8*)&wds[(wv * 16 + (l & 15)) * 72 + fo];
#pragma unroll
            for (int pt = 0; pt < 4; ++pt) {
                bf16x8 a = *(const bf16x8*)&vs[(pt * 16 + (l & 15)) * 72 + fo];
                acc[pt] = __builtin_amdgcn_mfma_f32_16x16x32_bf16(a, bfr, acc[pt], 0, 0, 0);
            }
        }
        __syncthreads();
    }
    int o = wv * 16 + (l & 15);
    float bo = b_dcn[o];
    int q = l >> 4;
    float* dst = out + ((long)(b * OO + o) * HH + h) * WW + w0;
#pragma unroll
    for (int pt = 0; pt < 4; ++pt)
#pragma unroll
        for (int r = 0; r < 4; ++r)
            dst[pt * 16 + q * 4 + r] = acc[pt][r] + bo;
}

// ---------------------------------------------------------------------------
extern "C" void kernel_launch(void* const* d_in, const int* in_sizes, int n_in,
                              void* d_out, int out_size, void* d_ws, size_t ws_size,
                              hipStream_t stream) {
    const float* x     = (const float*)d_in[0];
    const float* w_off = (const float*)d_in[1];
    const float* b_off = (const float*)d_in[2];
    const float* w_dcn = (const float*)d_in[3];
    const float* b_dcn = (const float*)d_in[4];
    float* out = (float*)d_out;

    char* ws = (char*)d_ws;
    float*          xh  = (float*)ws;                         // 16,777,216 B
    float*          ofb = (float*)(ws + 16777216);            //  4,718,592 B
    unsigned short* wdt = (unsigned short*)(ws + 21495808);   //     73,728 B
    unsigned short* wot = (unsigned short*)(ws + 21569536);   //     36,864 B

    hipLaunchKernelGGL(transpose_x, dim3(2, 128, 4), dim3(256), 0, stream, x, xh);
    hipLaunchKernelGGL(prep_w, dim3(216), dim3(256), 0, stream, w_dcn, w_off, wdt, wot);
    hipLaunchKernelGGL(offset_mfma, dim3(2, 128, 4), dim3(256), 0, stream,
                       xh, wot, b_off, ofb);
    hipLaunchKernelGGL(deform_mfma, dim3(2, 128, 4), dim3(256), 0, stream,
                       xh, ofb, wdt, b_dcn, out);
}

// Round 4
// 168.745 us; speedup vs baseline: 1.5208x; 1.0468x over previous
//
#include <hip/hip_runtime.h>

#define BB 4
#define HH 128
#define WW 128
#define CC 64
#define OO 64
#define HWSZ (HH*WW)

typedef short bf16x8 __attribute__((ext_vector_type(8)));
typedef float f32x4  __attribute__((ext_vector_type(4)));

__device__ __forceinline__ unsigned short f2bf(float f) {
    unsigned u = __float_as_uint(f);
    u = (u + 0x7FFFu + ((u >> 16) & 1u)) >> 16;
    return (unsigned short)u;
}
__device__ __forceinline__ float bf2f(unsigned short s) {
    return __uint_as_float(((unsigned)s) << 16);
}

// ---------------------------------------------------------------------------
// K0: x NCHW fp32 -> NHWC bf16 (LDS-tiled transpose, +1 pad)
// ---------------------------------------------------------------------------
__global__ __launch_bounds__(256) void transpose_x(const float* __restrict__ x,
                                                   unsigned short* __restrict__ xhb) {
    __shared__ float tile[64 * 65];
    int w0 = blockIdx.x * 64, h = blockIdx.y, b = blockIdx.z;
    int t = threadIdx.x;
    const float* xb = x + ((long)b * CC * HWSZ) + h * WW + w0;
#pragma unroll
    for (int i = 0; i < 16; ++i) {
        int idx = i * 256 + t; int c = idx >> 6, w = idx & 63;
        tile[c * 65 + w] = xb[c * HWSZ + w];
    }
    __syncthreads();
    unsigned short* xo = xhb + ((long)((b * HH + h) * WW + w0)) * CC;
#pragma unroll
    for (int i = 0; i < 8; ++i) {
        int idx = i * 256 + t; int w = idx >> 5, c = (idx & 31) * 2;
        ushort2 u;
        u.x = f2bf(tile[c * 65 + w]);
        u.y = f2bf(tile[(c + 1) * 65 + w]);
        *(ushort2*)(xo + w * CC + c) = u;
    }
}

// ---------------------------------------------------------------------------
// K1: weight repack -> bf16.  wdt[k][o][c], wot[k][oc(pad32)][c]
// ---------------------------------------------------------------------------
__global__ __launch_bounds__(256) void prep_w(const float* __restrict__ wd,
                                              const float* __restrict__ wo,
                                              unsigned short* __restrict__ wdt,
                                              unsigned short* __restrict__ wot) {
    int i = blockIdx.x * 256 + threadIdx.x;
    if (i < 9 * 64 * 64) {
        int k = i >> 12, r = i & 4095, o = r >> 6, c = r & 63;
        wdt[i] = f2bf(wd[(o * 64 + c) * 9 + k]);
    }
    int j = i - 9 * 64 * 64;
    if (j >= 0 && j < 9 * 32 * 64) {
        int k = j >> 11, r = j & 2047, oc = r >> 6, c = r & 63;
        wot[j] = f2bf(oc < 18 ? wo[(oc * 64 + c) * 9 + k] : 0.0f);
    }
}

// ---------------------------------------------------------------------------
// K2: offset conv — barrier-free implicit-GEMM MFMA. Wave = 16 px x 32 oc.
// A-fragments load directly from bf16 NHWC x; B from cached wot. No LDS.
// ---------------------------------------------------------------------------
__global__ __launch_bounds__(256) void offset_mfma(const unsigned short* __restrict__ xhb,
                                                   const unsigned short* __restrict__ wot,
                                                   const float* __restrict__ b_off,
                                                   float* __restrict__ offb) {
    int w0 = blockIdx.x * 64, h = blockIdx.y, b = blockIdx.z;
    int t = threadIdx.x;
    int l = t & 63, wv = t >> 6;
    int m = l & 15, q = l >> 4;
    int px0 = wv * 16;

    f32x4 acc0 = {0.f, 0.f, 0.f, 0.f}, acc1 = {0.f, 0.f, 0.f, 0.f};
    const bf16x8 zerov = {0, 0, 0, 0, 0, 0, 0, 0};

#pragma unroll
    for (int k = 0; k < 9; ++k) {
        int ky = k / 3, kx = k - ky * 3;
        int y = h + ky - 1;
        int xw = w0 + px0 + m + kx - 1;
        bool ok = ((unsigned)y < HH) && ((unsigned)xw < WW);
        const unsigned short* ap = xhb + ((long)((b * HH + y) * WW + xw)) * CC + q * 8;
        const unsigned short* bp = wot + k * 2048 + q * 8;
#pragma unroll
        for (int c0 = 0; c0 < 64; c0 += 32) {
            bf16x8 a = ok ? *(const bf16x8*)(ap + c0) : zerov;
            bf16x8 b0 = *(const bf16x8*)(bp + m * 64 + c0);
            bf16x8 b1 = *(const bf16x8*)(bp + (16 + m) * 64 + c0);
            acc0 = __builtin_amdgcn_mfma_f32_16x16x32_bf16(a, b0, acc0, 0, 0, 0);
            acc1 = __builtin_amdgcn_mfma_f32_16x16x32_bf16(a, b1, acc1, 0, 0, 0);
        }
    }
    // C/D: col = oc = m, row(px) = q*4 + r
    float* dst = offb + ((long)((b * HH + h) * WW + w0 + px0)) * 18;
    float bo0 = b_off[m];
#pragma unroll
    for (int r = 0; r < 4; ++r)
        dst[(q * 4 + r) * 18 + m] = acc0[r] + bo0;
    if (m < 2) {
        float bo1 = b_off[16 + m];
#pragma unroll
        for (int r = 0; r < 4; ++r)
            dst[(q * 4 + r) * 18 + 16 + m] = acc1[r] + bo1;
    }
}

// ---------------------------------------------------------------------------
// K3: deform conv — barrier-free. Wave = 16 px x 64 o. Lane l samples its own
// A-fragment (px = l&15, channels (l>>4)*8 + {0..7, 32..39}) via bilinear
// interp of bf16 NHWC x; B-fragments from cached wdt. No LDS, no barriers.
// ---------------------------------------------------------------------------
__global__ __launch_bounds__(256) void deform_mfma(const unsigned short* __restrict__ xhb,
                                                   const float* __restrict__ offb,
                                                   const unsigned short* __restrict__ wdt,
                                                   const float* __restrict__ b_dcn,
                                                   float* __restrict__ out) {
    int w0 = blockIdx.x * 64, h = blockIdx.y, b = blockIdx.z;
    int t = threadIdx.x;
    int l = t & 63, wv = t >> 6;
    int m = l & 15, q = l >> 4;
    int pxg = w0 + wv * 16 + m;          // this lane's pixel (w coordinate)

    // preload this pixel's 18 offsets (dy,dx per k)
    const float* op = offb + ((long)((b * HH + h) * WW + pxg)) * 18;
    float2 offv[9];
#pragma unroll
    for (int k = 0; k < 9; ++k) offv[k] = *(const float2*)(op + 2 * k);

    f32x4 acc[4];
#pragma unroll
    for (int i = 0; i < 4; ++i) acc[i] = f32x4{0.f, 0.f, 0.f, 0.f};

    const unsigned short* xb = xhb + (long)b * HWSZ * CC;

#pragma unroll
    for (int k = 0; k < 9; ++k) {
        int ky = k / 3, kx = k - ky * 3;
        float py  = (float)(h + ky - 1) + offv[k].x;
        float pxf = (float)(pxg + kx - 1) + offv[k].y;
        float y0f = floorf(py), x0f = floorf(pxf);
        float wy = py - y0f, wx = pxf - x0f;
        int y0 = (int)y0f, x0 = (int)x0f, y1 = y0 + 1, x1 = x0 + 1;
        float wy0 = 1.f - wy, wx0 = 1.f - wx;
        bool vy0 = (unsigned)y0 < HH, vy1 = (unsigned)y1 < HH;
        bool vx0 = (unsigned)x0 < WW, vx1 = (unsigned)x1 < WW;
        int y0c = min(max(y0, 0), HH - 1), y1c = min(max(y1, 0), HH - 1);
        int x0c = min(max(x0, 0), WW - 1), x1c = min(max(x1, 0), WW - 1);
        float cw0 = (vy0 && vx0) ? wy0 * wx0 : 0.f;
        float cw1 = (vy0 && vx1) ? wy0 * wx  : 0.f;
        float cw2 = (vy1 && vx0) ? wy  * wx0 : 0.f;
        float cw3 = (vy1 && vx1) ? wy  * wx  : 0.f;
        const unsigned short* p00 = xb + (y0c * WW + x0c) * CC + q * 8;
        const unsigned short* p01 = xb + (y0c * WW + x1c) * CC + q * 8;
        const unsigned short* p10 = xb + (y1c * WW + x0c) * CC + q * 8;
        const unsigned short* p11 = xb + (y1c * WW + x1c) * CC + q * 8;
        const unsigned short* bp = wdt + k * 4096 + q * 8;
#pragma unroll
        for (int c0 = 0; c0 < 64; c0 += 32) {
            bf16x8 s00 = *(const bf16x8*)(p00 + c0);
            bf16x8 s01 = *(const bf16x8*)(p01 + c0);
            bf16x8 s10 = *(const bf16x8*)(p10 + c0);
            bf16x8 s11 = *(const bf16x8*)(p11 + c0);
            bf16x8 a;
#pragma unroll
            for (int e = 0; e < 8; ++e) {
                float v = cw0 * bf2f((unsigned short)s00[e])
                        + cw1 * bf2f((unsigned short)s01[e])
                        + cw2 * bf2f((unsigned short)s10[e])
                        + cw3 * bf2f((unsigned short)s11[e]);
                a[e] = (short)f2bf(v);
            }
#pragma unroll
            for (int ot = 0; ot < 4; ++ot) {
                bf16x8 bfr = *(const bf16x8*)(bp + (ot * 16 + m) * 64 + c0);
                acc[ot] = __builtin_amdgcn_mfma_f32_16x16x32_bf16(a, bfr, acc[ot], 0, 0, 0);
            }
        }
    }
    // C/D: col = o = ot*16 + m, row(px) = q*4 + r -> contiguous in w: float4
#pragma unroll
    for (int ot = 0; ot < 4; ++ot) {
        int o = ot * 16 + m;
        float bo = b_dcn[o];
        f32x4 r = acc[ot];
        r[0] += bo; r[1] += bo; r[2] += bo; r[3] += bo;
        float* dst = out + ((long)(b * OO + o)) * HWSZ + h * WW + w0 + wv * 16 + q * 4;
        *(f32x4*)dst = r;
    }
}

// ---------------------------------------------------------------------------
extern "C" void kernel_launch(void* const* d_in, const int* in_sizes, int n_in,
                              void* d_out, int out_size, void* d_ws, size_t ws_size,
                              hipStream_t stream) {
    const float* x     = (const float*)d_in[0];
    const float* w_off = (const float*)d_in[1];
    const float* b_off = (const float*)d_in[2];
    const float* w_dcn = (const float*)d_in[3];
    const float* b_dcn = (const float*)d_in[4];
    float* out = (float*)d_out;

    char* ws = (char*)d_ws;
    unsigned short* xhb = (unsigned short*)ws;                // 8,388,608 B
    float*          ofb = (float*)(ws + 8388608);             // 4,718,592 B
    unsigned short* wdt = (unsigned short*)(ws + 13107200);   //    73,728 B
    unsigned short* wot = (unsigned short*)(ws + 13180928);   //    36,864 B

    hipLaunchKernelGGL(transpose_x, dim3(2, 128, 4), dim3(256), 0, stream, x, xhb);
    hipLaunchKernelGGL(prep_w, dim3(216), dim3(256), 0, stream, w_dcn, w_off, wdt, wot);
    hipLaunchKernelGGL(offset_mfma, dim3(2, 128, 4), dim3(256), 0, stream,
                       xhb, wot, b_off, ofb);
    hipLaunchKernelGGL(deform_mfma, dim3(2, 128, 4), dim3(256), 0, stream,
                       xhb, ofb, wdt, b_dcn, out);
}

// Round 5
// 166.402 us; speedup vs baseline: 1.5423x; 1.0141x over previous
//
#include <hip/hip_runtime.h>

#define BB 4
#define HH 128
#define WW 128
#define CC 64
#define OO 64
#define HWSZ (HH*WW)

typedef short bf16x8 __attribute__((ext_vector_type(8)));
typedef float f32x4  __attribute__((ext_vector_type(4)));

__device__ __forceinline__ unsigned short f2bf(float f) {
    unsigned u = __float_as_uint(f);
    u = (u + 0x7FFFu + ((u >> 16) & 1u)) >> 16;
    return (unsigned short)u;
}
__device__ __forceinline__ float bf2f(unsigned short s) {
    return __uint_as_float(((unsigned)s) << 16);
}

// ---------------------------------------------------------------------------
// K0: x NCHW fp32 -> NHWC bf16 (LDS-tiled transpose, +1 pad)
// ---------------------------------------------------------------------------
__global__ __launch_bounds__(256) void transpose_x(const float* __restrict__ x,
                                                   unsigned short* __restrict__ xhb) {
    __shared__ float tile[64 * 65];
    int w0 = blockIdx.x * 64, h = blockIdx.y, b = blockIdx.z;
    int t = threadIdx.x;
    const float* xb = x + ((long)b * CC * HWSZ) + h * WW + w0;
#pragma unroll
    for (int i = 0; i < 16; ++i) {
        int idx = i * 256 + t; int c = idx >> 6, w = idx & 63;
        tile[c * 65 + w] = xb[c * HWSZ + w];
    }
    __syncthreads();
    unsigned short* xo = xhb + ((long)((b * HH + h) * WW + w0)) * CC;
#pragma unroll
    for (int i = 0; i < 8; ++i) {
        int idx = i * 256 + t; int w = idx >> 5, c = (idx & 31) * 2;
        ushort2 u;
        u.x = f2bf(tile[c * 65 + w]);
        u.y = f2bf(tile[(c + 1) * 65 + w]);
        *(ushort2*)(xo + w * CC + c) = u;
    }
}

// ---------------------------------------------------------------------------
// K1: weight repack -> bf16.  wdt[k][o][c], wot[k][oc(pad32)][c]
// ---------------------------------------------------------------------------
__global__ __launch_bounds__(256) void prep_w(const float* __restrict__ wd,
                                              const float* __restrict__ wo,
                                              unsigned short* __restrict__ wdt,
                                              unsigned short* __restrict__ wot) {
    int i = blockIdx.x * 256 + threadIdx.x;
    if (i < 9 * 64 * 64) {
        int k = i >> 12, r = i & 4095, o = r >> 6, c = r & 63;
        wdt[i] = f2bf(wd[(o * 64 + c) * 9 + k]);
    }
    int j = i - 9 * 64 * 64;
    if (j >= 0 && j < 9 * 32 * 64) {
        int k = j >> 11, r = j & 2047, oc = r >> 6, c = r & 63;
        wot[j] = f2bf(oc < 18 ? wo[(oc * 64 + c) * 9 + k] : 0.0f);
    }
}

// ---------------------------------------------------------------------------
// K2: fused offset-conv + deformable conv. Block = (b,h,64px).
// Phase 1: offset conv via MFMA (wave = its 16 px), result -> LDS offs.
// Phase 2: deform conv, lane-owned bilinear sampling into A-fragments,
// explicit register double-buffering of the 8 corner loads per k so the
// compiler emits fine-grained vmcnt waits (k+1 loads in flight during k's
// convert+MFMA). No global offset round-trip; one barrier total.
// ---------------------------------------------------------------------------
__global__ __launch_bounds__(256) void fused_dcn(const unsigned short* __restrict__ xhb,
                                                 const unsigned short* __restrict__ wot,
                                                 const float* __restrict__ b_off,
                                                 const unsigned short* __restrict__ wdt,
                                                 const float* __restrict__ b_dcn,
                                                 float* __restrict__ out) {
    __shared__ float offs[64 * 20];          // [px][oc(18, stride 20)]
    int w0 = blockIdx.x * 64, h = blockIdx.y, b = blockIdx.z;
    int t = threadIdx.x;
    int l = t & 63, wv = t >> 6;
    int m = l & 15, q = l >> 4;

    const unsigned short* xb = xhb + (long)b * HWSZ * CC;
    const bf16x8 zerov = {0, 0, 0, 0, 0, 0, 0, 0};

    // ================= phase 1: offset conv =================
    {
        int px0 = wv * 16;
        f32x4 acc0 = {0.f, 0.f, 0.f, 0.f}, acc1 = {0.f, 0.f, 0.f, 0.f};
        bf16x8 ac0, ac1;
        {   // prefetch k = 0  (ky=0,kx=0)
            int y = h - 1, xw = w0 + px0 + m - 1;
            bool ok = ((unsigned)y < HH) && ((unsigned)xw < WW);
            const bf16x8* p = (const bf16x8*)(xb + ((long)(y * WW + xw)) * CC + q * 8);
            ac0 = ok ? p[0] : zerov;
            ac1 = ok ? p[4] : zerov;
        }
#pragma unroll
        for (int k = 0; k < 9; ++k) {
            bf16x8 an0 = zerov, an1 = zerov;
            if (k < 8) {
                int k2 = k + 1, ky = k2 / 3, kx = k2 - ky * 3;
                int y = h + ky - 1, xw = w0 + px0 + m + kx - 1;
                bool ok = ((unsigned)y < HH) && ((unsigned)xw < WW);
                const bf16x8* p = (const bf16x8*)(xb + ((long)(y * WW + xw)) * CC + q * 8);
                an0 = ok ? p[0] : zerov;
                an1 = ok ? p[4] : zerov;
            }
            const unsigned short* bp = wot + k * 2048 + q * 8;
            bf16x8 b00 = *(const bf16x8*)(bp + m * 64);
            bf16x8 b10 = *(const bf16x8*)(bp + (16 + m) * 64);
            bf16x8 b01 = *(const bf16x8*)(bp + m * 64 + 32);
            bf16x8 b11 = *(const bf16x8*)(bp + (16 + m) * 64 + 32);
            acc0 = __builtin_amdgcn_mfma_f32_16x16x32_bf16(ac0, b00, acc0, 0, 0, 0);
            acc1 = __builtin_amdgcn_mfma_f32_16x16x32_bf16(ac0, b10, acc1, 0, 0, 0);
            acc0 = __builtin_amdgcn_mfma_f32_16x16x32_bf16(ac1, b01, acc0, 0, 0, 0);
            acc1 = __builtin_amdgcn_mfma_f32_16x16x32_bf16(ac1, b11, acc1, 0, 0, 0);
            ac0 = an0; ac1 = an1;
        }
        // C/D: row(px) = q*4+r, col(oc) = m
        float bo0 = b_off[m];
#pragma unroll
        for (int r = 0; r < 4; ++r)
            offs[(px0 + q * 4 + r) * 20 + m] = acc0[r] + bo0;
        if (m < 2) {
            float bo1 = b_off[16 + m];
#pragma unroll
            for (int r = 0; r < 4; ++r)
                offs[(px0 + q * 4 + r) * 20 + 16 + m] = acc1[r] + bo1;
        }
    }
    __syncthreads();

    // ================= phase 2: deform conv =================
    int pxl = wv * 16 + m;                 // this lane's pixel (within row tile)
    int pxg = w0 + pxl;                    // global w coordinate
    const float* offrow = &offs[pxl * 20];

    f32x4 acc[4];
#pragma unroll
    for (int i = 0; i < 4; ++i) acc[i] = f32x4{0.f, 0.f, 0.f, 0.f};

    // current-k corner data (2 chunks x 4 corners) + weights, next-k buffered
    bf16x8 c00a, c01a, c10a, c11a, c00b, c01b, c10b, c11b;
    float cw0, cw1, cw2, cw3;

    {   // prefetch k = 0
        float2 ov = *(const float2*)(offrow + 0);
        float py  = (float)(h - 1) + ov.x;
        float pxf = (float)(pxg - 1) + ov.y;
        float y0f = floorf(py), x0f = floorf(pxf);
        float wy = py - y0f, wx = pxf - x0f;
        int y0 = (int)y0f, x0 = (int)x0f, y1 = y0 + 1, x1 = x0 + 1;
        bool vy0 = (unsigned)y0 < HH, vy1 = (unsigned)y1 < HH;
        bool vx0 = (unsigned)x0 < WW, vx1 = (unsigned)x1 < WW;
        int y0c = min(max(y0, 0), HH - 1), y1c = min(max(y1, 0), HH - 1);
        int x0c = min(max(x0, 0), WW - 1), x1c = min(max(x1, 0), WW - 1);
        cw0 = (vy0 && vx0) ? (1.f - wy) * (1.f - wx) : 0.f;
        cw1 = (vy0 && vx1) ? (1.f - wy) * wx : 0.f;
        cw2 = (vy1 && vx0) ? wy * (1.f - wx) : 0.f;
        cw3 = (vy1 && vx1) ? wy * wx : 0.f;
        const bf16x8* p00 = (const bf16x8*)(xb + (y0c * WW + x0c) * CC + q * 8);
        const bf16x8* p01 = (const bf16x8*)(xb + (y0c * WW + x1c) * CC + q * 8);
        const bf16x8* p10 = (const bf16x8*)(xb + (y1c * WW + x0c) * CC + q * 8);
        const bf16x8* p11 = (const bf16x8*)(xb + (y1c * WW + x1c) * CC + q * 8);
        c00a = p00[0]; c01a = p01[0]; c10a = p10[0]; c11a = p11[0];
        c00b = p00[4]; c01b = p01[4]; c10b = p10[4]; c11b = p11[4];
    }

#pragma unroll
    for (int k = 0; k < 9; ++k) {
        // ---- issue next-k corner loads (8 loads in flight over this iter) ----
        bf16x8 n00a, n01a, n10a, n11a, n00b, n01b, n10b, n11b;
        float nw0 = 0.f, nw1 = 0.f, nw2 = 0.f, nw3 = 0.f;
        if (k < 8) {
            int k2 = k + 1, ky = k2 / 3, kx = k2 - ky * 3;
            float2 ov = *(const float2*)(offrow + 2 * k2);
            float py  = (float)(h + ky - 1) + ov.x;
            float pxf = (float)(pxg + kx - 1) + ov.y;
            float y0f = floorf(py), x0f = floorf(pxf);
            float wy = py - y0f, wx = pxf - x0f;
            int y0 = (int)y0f, x0 = (int)x0f, y1 = y0 + 1, x1 = x0 + 1;
            bool vy0 = (unsigned)y0 < HH, vy1 = (unsigned)y1 < HH;
            bool vx0 = (unsigned)x0 < WW, vx1 = (unsigned)x1 < WW;
            int y0c = min(max(y0, 0), HH - 1), y1c = min(max(y1, 0), HH - 1);
            int x0c = min(max(x0, 0), WW - 1), x1c = min(max(x1, 0), WW - 1);
            nw0 = (vy0 && vx0) ? (1.f - wy) * (1.f - wx) : 0.f;
            nw1 = (vy0 && vx1) ? (1.f - wy) * wx : 0.f;
            nw2 = (vy1 && vx0) ? wy * (1.f - wx) : 0.f;
            nw3 = (vy1 && vx1) ? wy * wx : 0.f;
            const bf16x8* p00 = (const bf16x8*)(xb + (y0c * WW + x0c) * CC + q * 8);
            const bf16x8* p01 = (const bf16x8*)(xb + (y0c * WW + x1c) * CC + q * 8);
            const bf16x8* p10 = (const bf16x8*)(xb + (y1c * WW + x0c) * CC + q * 8);
            const bf16x8* p11 = (const bf16x8*)(xb + (y1c * WW + x1c) * CC + q * 8);
            n00a = p00[0]; n01a = p01[0]; n10a = p10[0]; n11a = p11[0];
            n00b = p00[4]; n01b = p01[4]; n10b = p10[4]; n11b = p11[4];
        } else {
            n00a = n01a = n10a = n11a = zerov;
            n00b = n01b = n10b = n11b = zerov;
        }

        // ---- issue this k's weight loads early (latency hides under convert) --
        const unsigned short* bp = wdt + k * 4096 + q * 8;
        bf16x8 wf0 = *(const bf16x8*)(bp + (0 * 16 + m) * 64);
        bf16x8 wf1 = *(const bf16x8*)(bp + (0 * 16 + m) * 64 + 32);
        bf16x8 wf2 = *(const bf16x8*)(bp + (1 * 16 + m) * 64);
        bf16x8 wf3 = *(const bf16x8*)(bp + (1 * 16 + m) * 64 + 32);
        bf16x8 wf4 = *(const bf16x8*)(bp + (2 * 16 + m) * 64);
        bf16x8 wf5 = *(const bf16x8*)(bp + (2 * 16 + m) * 64 + 32);
        bf16x8 wf6 = *(const bf16x8*)(bp + (3 * 16 + m) * 64);
        bf16x8 wf7 = *(const bf16x8*)(bp + (3 * 16 + m) * 64 + 32);

        // ---- convert current corners -> A fragments ----
        bf16x8 a0, a1;
#pragma unroll
        for (int e = 0; e < 8; ++e) {
            float v = cw0 * bf2f((unsigned short)c00a[e])
                    + cw1 * bf2f((unsigned short)c01a[e])
                    + cw2 * bf2f((unsigned short)c10a[e])
                    + cw3 * bf2f((unsigned short)c11a[e]);
            a0[e] = (short)f2bf(v);
            float u = cw0 * bf2f((unsigned short)c00b[e])
                    + cw1 * bf2f((unsigned short)c01b[e])
                    + cw2 * bf2f((unsigned short)c10b[e])
                    + cw3 * bf2f((unsigned short)c11b[e]);
            a1[e] = (short)f2bf(u);
        }

        acc[0] = __builtin_amdgcn_mfma_f32_16x16x32_bf16(a0, wf0, acc[0], 0, 0, 0);
        acc[0] = __builtin_amdgcn_mfma_f32_16x16x32_bf16(a1, wf1, acc[0], 0, 0, 0);
        acc[1] = __builtin_amdgcn_mfma_f32_16x16x32_bf16(a0, wf2, acc[1], 0, 0, 0);
        acc[1] = __builtin_amdgcn_mfma_f32_16x16x32_bf16(a1, wf3, acc[1], 0, 0, 0);
        acc[2] = __builtin_amdgcn_mfma_f32_16x16x32_bf16(a0, wf4, acc[2], 0, 0, 0);
        acc[2] = __builtin_amdgcn_mfma_f32_16x16x32_bf16(a1, wf5, acc[2], 0, 0, 0);
        acc[3] = __builtin_amdgcn_mfma_f32_16x16x32_bf16(a0, wf6, acc[3], 0, 0, 0);
        acc[3] = __builtin_amdgcn_mfma_f32_16x16x32_bf16(a1, wf7, acc[3], 0, 0, 0);

        c00a = n00a; c01a = n01a; c10a = n10a; c11a = n11a;
        c00b = n00b; c01b = n01b; c10b = n10b; c11b = n11b;
        cw0 = nw0; cw1 = nw1; cw2 = nw2; cw3 = nw3;
    }

    // ---- epilogue: C/D row(px)=q*4+r, col(o)=ot*16+m ----
#pragma unroll
    for (int ot = 0; ot < 4; ++ot) {
        int o = ot * 16 + m;
        float bo = b_dcn[o];
        f32x4 r = acc[ot];
        r[0] += bo; r[1] += bo; r[2] += bo; r[3] += bo;
        float* dst = out + ((long)(b * OO + o)) * HWSZ + h * WW + w0 + wv * 16 + q * 4;
        *(f32x4*)dst = r;
    }
}

// ---------------------------------------------------------------------------
extern "C" void kernel_launch(void* const* d_in, const int* in_sizes, int n_in,
                              void* d_out, int out_size, void* d_ws, size_t ws_size,
                              hipStream_t stream) {
    const float* x     = (const float*)d_in[0];
    const float* w_off = (const float*)d_in[1];
    const float* b_off = (const float*)d_in[2];
    const float* w_dcn = (const float*)d_in[3];
    const float* b_dcn = (const float*)d_in[4];
    float* out = (float*)d_out;

    char* ws = (char*)d_ws;
    unsigned short* xhb = (unsigned short*)ws;              // 8,388,608 B
    unsigned short* wdt = (unsigned short*)(ws + 8388608);  //    73,728 B
    unsigned short* wot = (unsigned short*)(ws + 8462336);  //    36,864 B

    hipLaunchKernelGGL(transpose_x, dim3(2, 128, 4), dim3(256), 0, stream, x, xhb);
    hipLaunchKernelGGL(prep_w, dim3(216), dim3(256), 0, stream, w_dcn, w_off, wdt, wot);
    hipLaunchKernelGGL(fused_dcn, dim3(2, 128, 4), dim3(256), 0, stream,
                       xhb, wot, b_off, wdt, b_dcn, out);
}

// Round 6
// 126.235 us; speedup vs baseline: 2.0330x; 1.3182x over previous
//
#include <hip/hip_runtime.h>

#define HH 128
#define WW 128
#define CC 64
#define OO 64
#define HWSZ (HH*WW)

typedef short bf16x8 __attribute__((ext_vector_type(8)));
typedef float f32x4  __attribute__((ext_vector_type(4)));

__device__ __forceinline__ unsigned short f2bf(float f) {
    unsigned u = __float_as_uint(f);
    u = (u + 0x7FFFu + ((u >> 16) & 1u)) >> 16;
    return (unsigned short)u;
}
__device__ __forceinline__ float bf2f(unsigned short s) {
    return __uint_as_float(((unsigned)s) << 16);
}

// ---------------------------------------------------------------------------
// K0: x NCHW fp32 -> NHWC bf16 (LDS-tiled transpose, +1 pad)
// ---------------------------------------------------------------------------
__global__ __launch_bounds__(256) void transpose_x(const float* __restrict__ x,
                                                   unsigned short* __restrict__ xhb) {
    __shared__ float tile[64 * 65];
    int w0 = blockIdx.x * 64, h = blockIdx.y, b = blockIdx.z;
    int t = threadIdx.x;
    const float* xb = x + ((long)b * CC * HWSZ) + h * WW + w0;
#pragma unroll
    for (int i = 0; i < 16; ++i) {
        int idx = i * 256 + t; int c = idx >> 6, w = idx & 63;
        tile[c * 65 + w] = xb[c * HWSZ + w];
    }
    __syncthreads();
    unsigned short* xo = xhb + ((long)((b * HH + h) * WW + w0)) * CC;
#pragma unroll
    for (int i = 0; i < 8; ++i) {
        int idx = i * 256 + t; int w = idx >> 5, c = (idx & 31) * 2;
        ushort2 u;
        u.x = f2bf(tile[c * 65 + w]);
        u.y = f2bf(tile[(c + 1) * 65 + w]);
        *(ushort2*)(xo + w * CC + c) = u;
    }
}

// ---------------------------------------------------------------------------
// K1: weight repack -> bf16.  wdt[k][o][c], wot[k][oc(pad32)][c]
// ---------------------------------------------------------------------------
__global__ __launch_bounds__(256) void prep_w(const float* __restrict__ wd,
                                              const float* __restrict__ wo,
                                              unsigned short* __restrict__ wdt,
                                              unsigned short* __restrict__ wot) {
    int i = blockIdx.x * 256 + threadIdx.x;
    if (i < 9 * 64 * 64) {
        int k = i >> 12, r = i & 4095, o = r >> 6, c = r & 63;
        wdt[i] = f2bf(wd[(o * 64 + c) * 9 + k]);
    }
    int j = i - 9 * 64 * 64;
    if (j >= 0 && j < 9 * 32 * 64) {
        int k = j >> 11, r = j & 2047, oc = r >> 6, c = r & 63;
        wot[j] = f2bf(oc < 18 ? wo[(oc * 64 + c) * 9 + k] : 0.0f);
    }
}

// ---------------------------------------------------------------------------
// K2: offset conv. Block = (b,h,64px). Stage rows h-1..h+1 (66 px x 64ch
// bf16, 72-stride pad) into LDS ONCE; one barrier; then 9 k-iters of pure
// ds_read + MFMA (B slices from L1-hot wot). No global loads in k-loop.
// ---------------------------------------------------------------------------
__global__ __launch_bounds__(256) void offset_tile(const unsigned short* __restrict__ xhb,
                                                   const unsigned short* __restrict__ wot,
                                                   const float* __restrict__ b_off,
                                                   float* __restrict__ ofb) {
    __shared__ unsigned short xr[3 * 68 * 72];   // [row][px(66,pad68)][ch(64,pad72)]
    int w0 = blockIdx.x * 64, h = blockIdx.y, b = blockIdx.z;
    int t = threadIdx.x;

    // stage: 3 rows x 66 px x 8 chunks(16B) = 1584 chunk-copies
#pragma unroll
    for (int i = 0; i < 7; ++i) {
        int idx = i * 256 + t;
        if (idx < 1584) {
            int r = idx / 528;
            int rem = idx - r * 528;
            int p = rem >> 3, cc = rem & 7;
            int y = h + r - 1, wx = w0 - 1 + p;
            uint4 v = make_uint4(0u, 0u, 0u, 0u);
            if (((unsigned)y < HH) && ((unsigned)wx < WW))
                v = *(const uint4*)(xhb + ((long)((b * HH + y) * WW + wx)) * CC + cc * 8);
            *(uint4*)&xr[(r * 68 + p) * 72 + cc * 8] = v;
        }
    }
    __syncthreads();

    int l = t & 63, wv = t >> 6;
    int m = l & 15, q = l >> 4;
    int px0 = wv * 16;
    f32x4 acc0 = {0.f, 0.f, 0.f, 0.f}, acc1 = {0.f, 0.f, 0.f, 0.f};

#pragma unroll
    for (int k = 0; k < 9; ++k) {
        int ky = k / 3, kx = k - ky * 3;
        const unsigned short* ar = &xr[(ky * 68 + px0 + m + kx) * 72 + q * 8];
        bf16x8 a0 = *(const bf16x8*)(ar);
        bf16x8 a1 = *(const bf16x8*)(ar + 32);
        const unsigned short* bp = wot + k * 2048 + q * 8;
        bf16x8 b00 = *(const bf16x8*)(bp + m * 64);
        bf16x8 b01 = *(const bf16x8*)(bp + m * 64 + 32);
        bf16x8 b10 = *(const bf16x8*)(bp + (16 + m) * 64);
        bf16x8 b11 = *(const bf16x8*)(bp + (16 + m) * 64 + 32);
        acc0 = __builtin_amdgcn_mfma_f32_16x16x32_bf16(a0, b00, acc0, 0, 0, 0);
        acc0 = __builtin_amdgcn_mfma_f32_16x16x32_bf16(a1, b01, acc0, 0, 0, 0);
        acc1 = __builtin_amdgcn_mfma_f32_16x16x32_bf16(a0, b10, acc1, 0, 0, 0);
        acc1 = __builtin_amdgcn_mfma_f32_16x16x32_bf16(a1, b11, acc1, 0, 0, 0);
    }
    // C/D: row(px) = q*4+r, col(oc) = m  -> ofb NHWC [b][h][w][18]
    float* dst = ofb + ((long)((b * HH + h) * WW + w0 + px0)) * 18;
    float bo0 = b_off[m];
#pragma unroll
    for (int r = 0; r < 4; ++r)
        dst[(q * 4 + r) * 18 + m] = acc0[r] + bo0;
    if (m < 2) {
        float bo1 = b_off[16 + m];
#pragma unroll
        for (int r = 0; r < 4; ++r)
            dst[(q * 4 + r) * 18 + 16 + m] = acc1[r] + bo1;
    }
}

// ---------------------------------------------------------------------------
// K3: deform conv. Block = (b,h,64px) x 64 o. Double-buffered LDS tiles
// (val[64][72] + wds[64][72] per buffer); per k: stage(k+1) = per-thread
// (px,16ch) bilinear gather (8 independent 16B loads) + weight-slice copy,
// overlapped with MFMA(k) from LDS; ONE barrier per k.
// ---------------------------------------------------------------------------
__global__ __launch_bounds__(256) void deform_tile(const unsigned short* __restrict__ xhb,
                                                   const float* __restrict__ ofb,
                                                   const unsigned short* __restrict__ wdt,
                                                   const float* __restrict__ b_dcn,
                                                   float* __restrict__ out) {
    __shared__ unsigned short lds[4 * 64 * 72];          // 36,864 B
    unsigned short* vbuf[2] = { lds,             lds + 2 * 64 * 72 };
    unsigned short* wbuf[2] = { lds + 64 * 72,   lds + 3 * 64 * 72 };

    int w0 = blockIdx.x * 64, h = blockIdx.y, b = blockIdx.z;
    int t = threadIdx.x;
    int l = t & 63, wv = t >> 6;
    int m = l & 15, q = l >> 4;
    int spx = t >> 2, q4 = t & 3;           // sampling role: pixel, 16-ch chunk

    const unsigned short* xb = xhb + (long)b * HWSZ * CC;

    // preload this thread's pixel offsets (9 x (dy,dx)) straight from global
    float2 o9[9];
    {
        const float* op = ofb + ((long)((b * HH + h) * WW + w0 + spx)) * 18;
#pragma unroll
        for (int k = 0; k < 9; ++k) o9[k] = *(const float2*)(op + 2 * k);
    }

    f32x4 acc[4];
#pragma unroll
    for (int i = 0; i < 4; ++i) acc[i] = f32x4{0.f, 0.f, 0.f, 0.f};

    // ---- stage helper (inlined twice via lambda) ----
    auto stage = [&](int k, unsigned short* vb, unsigned short* wb) {
        // weight slice: thread copies 32B of wdt[k] into 72-stride LDS rows
        {
            const unsigned short* wsrc = wdt + k * 4096;
            int o = t >> 2, cc = (t & 3) * 2;
            uint4 wv0 = *(const uint4*)(wsrc + o * 64 + cc * 8);
            uint4 wv1 = *(const uint4*)(wsrc + o * 64 + cc * 8 + 8);
            *(uint4*)&wb[o * 72 + cc * 8] = wv0;
            *(uint4*)&wb[o * 72 + cc * 8 + 8] = wv1;
        }
        // bilinear sample: this thread's (px, ch q4*16..q4*16+15)
        int ky = k / 3, kx = k - ky * 3;
        float py  = (float)(h + ky - 1) + o9[k].x;
        float pxf = (float)(w0 + spx + kx - 1) + o9[k].y;
        float y0f = floorf(py), x0f = floorf(pxf);
        float wy = py - y0f, wx = pxf - x0f;
        int y0 = (int)y0f, x0 = (int)x0f, y1 = y0 + 1, x1 = x0 + 1;
        bool vy0 = (unsigned)y0 < HH, vy1 = (unsigned)y1 < HH;
        bool vx0 = (unsigned)x0 < WW, vx1 = (unsigned)x1 < WW;
        int y0c = min(max(y0, 0), HH - 1), y1c = min(max(y1, 0), HH - 1);
        int x0c = min(max(x0, 0), WW - 1), x1c = min(max(x1, 0), WW - 1);
        float cw0 = (vy0 && vx0) ? (1.f - wy) * (1.f - wx) : 0.f;
        float cw1 = (vy0 && vx1) ? (1.f - wy) * wx : 0.f;
        float cw2 = (vy1 && vx0) ? wy * (1.f - wx) : 0.f;
        float cw3 = (vy1 && vx1) ? wy * wx : 0.f;
        const unsigned short* p00 = xb + (y0c * WW + x0c) * CC + q4 * 16;
        const unsigned short* p01 = xb + (y0c * WW + x1c) * CC + q4 * 16;
        const unsigned short* p10 = xb + (y1c * WW + x0c) * CC + q4 * 16;
        const unsigned short* p11 = xb + (y1c * WW + x1c) * CC + q4 * 16;
        bf16x8 s00a = *(const bf16x8*)p00,      s00b = *(const bf16x8*)(p00 + 8);
        bf16x8 s01a = *(const bf16x8*)p01,      s01b = *(const bf16x8*)(p01 + 8);
        bf16x8 s10a = *(const bf16x8*)p10,      s10b = *(const bf16x8*)(p10 + 8);
        bf16x8 s11a = *(const bf16x8*)p11,      s11b = *(const bf16x8*)(p11 + 8);
        bf16x8 a0, a1;
#pragma unroll
        for (int e = 0; e < 8; ++e) {
            float v = cw0 * bf2f((unsigned short)s00a[e])
                    + cw1 * bf2f((unsigned short)s01a[e])
                    + cw2 * bf2f((unsigned short)s10a[e])
                    + cw3 * bf2f((unsigned short)s11a[e]);
            a0[e] = (short)f2bf(v);
            float u = cw0 * bf2f((unsigned short)s00b[e])
                    + cw1 * bf2f((unsigned short)s01b[e])
                    + cw2 * bf2f((unsigned short)s10b[e])
                    + cw3 * bf2f((unsigned short)s11b[e]);
            a1[e] = (short)f2bf(u);
        }
        *(bf16x8*)&vb[spx * 72 + q4 * 16] = a0;
        *(bf16x8*)&vb[spx * 72 + q4 * 16 + 8] = a1;
    };

    stage(0, vbuf[0], wbuf[0]);
    __syncthreads();

#pragma unroll
    for (int k = 0; k < 9; ++k) {
        if (k < 8) stage(k + 1, vbuf[(k + 1) & 1], wbuf[(k + 1) & 1]);

        // MFMA phase from buffer k&1
        const unsigned short* vb = vbuf[k & 1];
        const unsigned short* wb = wbuf[k & 1];
        const unsigned short* ap = &vb[(wv * 16 + m) * 72 + q * 8];
        bf16x8 a0 = *(const bf16x8*)(ap);
        bf16x8 a1 = *(const bf16x8*)(ap + 32);
#pragma unroll
        for (int ot = 0; ot < 4; ++ot) {
            const unsigned short* bp = &wb[(ot * 16 + m) * 72 + q * 8];
            bf16x8 b0 = *(const bf16x8*)(bp);
            bf16x8 b1 = *(const bf16x8*)(bp + 32);
            acc[ot] = __builtin_amdgcn_mfma_f32_16x16x32_bf16(a0, b0, acc[ot], 0, 0, 0);
            acc[ot] = __builtin_amdgcn_mfma_f32_16x16x32_bf16(a1, b1, acc[ot], 0, 0, 0);
        }
        __syncthreads();
    }

    // epilogue: C/D row(px)=q*4+r (wave's px-tile = wv*16), col(o)=ot*16+m
#pragma unroll
    for (int ot = 0; ot < 4; ++ot) {
        int o = ot * 16 + m;
        float bo = b_dcn[o];
        f32x4 r = acc[ot];
        r[0] += bo; r[1] += bo; r[2] += bo; r[3] += bo;
        float* dst = out + ((long)(b * OO + o)) * HWSZ + h * WW + w0 + wv * 16 + q * 4;
        *(f32x4*)dst = r;
    }
}

// ---------------------------------------------------------------------------
extern "C" void kernel_launch(void* const* d_in, const int* in_sizes, int n_in,
                              void* d_out, int out_size, void* d_ws, size_t ws_size,
                              hipStream_t stream) {
    const float* x     = (const float*)d_in[0];
    const float* w_off = (const float*)d_in[1];
    const float* b_off = (const float*)d_in[2];
    const float* w_dcn = (const float*)d_in[3];
    const float* b_dcn = (const float*)d_in[4];
    float* out = (float*)d_out;

    char* ws = (char*)d_ws;
    unsigned short* xhb = (unsigned short*)ws;               //  8,388,608 B
    float*          ofb = (float*)(ws + 8388608);            //  4,718,592 B
    unsigned short* wdt = (unsigned short*)(ws + 13107200);  //     73,728 B
    unsigned short* wot = (unsigned short*)(ws + 13180928);  //     36,864 B

    hipLaunchKernelGGL(transpose_x, dim3(2, 128, 4), dim3(256), 0, stream, x, xhb);
    hipLaunchKernelGGL(prep_w, dim3(216), dim3(256), 0, stream, w_dcn, w_off, wdt, wot);
    hipLaunchKernelGGL(offset_tile, dim3(2, 128, 4), dim3(256), 0, stream,
                       xhb, wot, b_off, ofb);
    hipLaunchKernelGGL(deform_tile, dim3(2, 128, 4), dim3(256), 0, stream,
                       xhb, ofb, wdt, b_dcn, out);
}